// Round 6
// baseline (18054.039 us; speedup 1.0000x reference)
//
#include <hip/hip_runtime.h>
#include <math.h>

#define EMBED 768
#define HEADS 8
#define HDIM  96
#define NEG_MASK (-1.0e30f)

typedef unsigned short u16;
typedef unsigned int   u32;

__device__ __forceinline__ float bf2f(u16 u) {
    return __uint_as_float(((u32)u) << 16);
}
__device__ __forceinline__ u16 f2bf(float f) {
    u32 x = __float_as_uint(f);
    u32 r = (x + 0x7fffu + ((x >> 16) & 1u)) >> 16;
    return (u16)r;
}
__device__ __forceinline__ void unpack2(u32 w, float& lo, float& hi) {
    lo = __uint_as_float(w << 16);
    hi = __uint_as_float(w & 0xffff0000u);
}
__device__ __forceinline__ float wget(const void* p, size_t i, int wf) {
    return wf ? ((const float*)p)[i] : bf2f(((const u16*)p)[i]);
}

// ---------------- detection: one wave, no barriers ----------------
// blk[0]=wf (1 = wire f32), blk[1..8]=effect_lengths, blk[9]=us_rate
__global__ __launch_bounds__(64) void detect_kernel(const u16* __restrict__ x,
                                                    const int* __restrict__ el,
                                                    const int* __restrict__ usp,
                                                    int* __restrict__ blk) {
    int lane = threadIdx.x;
    int cnt = 0;
    for (int i = lane; i < 4096; i += 64) {
        u32 e = (x[i] >> 7) & 0xFFu;
        if (e >= 0xC0u) cnt++;   // |bf16| >= 2^65: impossible for sane activations
    }
#pragma unroll
    for (int off = 32; off > 0; off >>= 1) cnt += __shfl_xor(cnt, off, 64);
    if (lane == 0) {
        blk[0] = (cnt > 32) ? 1 : 0;   // f32 wire: ~25% of low-halfwords hit
        bool i64 = (el[1] == 0) && (el[3] == 0) && (el[5] == 0) && (el[7] == 0);
        for (int b = 0; b < 8; b++) blk[1 + b] = i64 ? el[2 * b] : el[b];
        blk[9] = usp[0];
    }
}

// ---------------- copies ----------------
__global__ void wire_to_f32(const void* __restrict__ in, size_t ioff,
                            float* __restrict__ out, int n,
                            const int* __restrict__ blk) {
    int i = blockIdx.x * blockDim.x + threadIdx.x;
    int wf = blk[0];
    if (i < n) out[i] = wget(in, ioff + (size_t)i, wf);
}
__global__ void wire_copy(const void* __restrict__ in, void* __restrict__ out,
                          int n, const int* __restrict__ blk) {
    int i = blockIdx.x * blockDim.x + threadIdx.x;
    int wf = blk[0];
    if (i < n) {
        if (wf) ((float*)out)[i] = ((const float*)in)[i];
        else    ((u16*)out)[i]   = ((const u16*)in)[i];
    }
}
__global__ void f32_to_out(const float* __restrict__ in, void* __restrict__ out,
                           size_t ooff, int n, const int* __restrict__ blk) {
    int i = blockIdx.x * blockDim.x + threadIdx.x;
    int wf = blk[0];
    if (i < n) {
        if (wf) ((float*)out)[ooff + i] = in[i];
        else    ((u16*)out)[ooff + i]   = f2bf(in[i]);
    }
}

// ---------------- LayerNorm (768 cols, 1 row/block, 256 thr) ----------------
// sel 0: in = f32 buffer; sel 2: in = wire-dtype buffer. Output bf16.
__global__ __launch_bounds__(256) void ln_kernel(const void* __restrict__ in,
                                                 size_t ioff, int sel,
                                                 const void* __restrict__ g,
                                                 const void* __restrict__ b,
                                                 u16* __restrict__ out,
                                                 const int* __restrict__ blk) {
    int wf = blk[0];
    int row = blockIdx.x, tid = threadIdx.x;
    size_t base = ioff + (size_t)row * EMBED;
    float v[3];
#pragma unroll
    for (int e = 0; e < 3; e++) {
        size_t idx = base + tid + e * 256;
        v[e] = (sel == 0) ? ((const float*)in)[idx] : wget(in, idx, wf);
    }
    float s = v[0] + v[1] + v[2];
    float q = v[0] * v[0] + v[1] * v[1] + v[2] * v[2];
#pragma unroll
    for (int off = 32; off > 0; off >>= 1) {
        s += __shfl_xor(s, off, 64);
        q += __shfl_xor(q, off, 64);
    }
    __shared__ float sb[8];
    int wid = tid >> 6, lane = tid & 63;
    if (lane == 0) { sb[wid] = s; sb[4 + wid] = q; }
    __syncthreads();
    if (tid == 0) {
        sb[0] = sb[0] + sb[1] + sb[2] + sb[3];
        sb[4] = sb[4] + sb[5] + sb[6] + sb[7];
    }
    __syncthreads();
    float mean = sb[0] * (1.0f / EMBED);
    float var  = sb[4] * (1.0f / EMBED) - mean * mean;
    float rs   = rsqrtf(var + 1e-5f);
    size_t obase = (size_t)row * EMBED;
#pragma unroll
    for (int e = 0; e < 3; e++) {
        int col = tid + e * 256;
        out[obase + col] = f2bf((v[e] - mean) * rs * wget(g, col, wf) + wget(b, col, wf));
    }
}

// ---------------- GEMM: C[M,N] (+)= op(A[M,K] @ W[woff.., ldw] (+bias[boff..]) (gelu))
// A bf16. W/bias wire dtype. tcmode: 0 = f32 accumulate; 1 = bf16 store; 3 = wire accumulate.
// flags: 1 bias, 2 exact GELU. M%64==0, N%64==0, K%16==0.
__global__ __launch_bounds__(256) void gemm_kernel(const u16* __restrict__ A,
                                                   const void* __restrict__ W,
                                                   size_t woff, int ldw,
                                                   const void* __restrict__ bias, int boff,
                                                   void* __restrict__ Cv, size_t coff,
                                                   int M, int N, int K, int flags,
                                                   int tcmode, const int* __restrict__ blk) {
    __shared__ float As[16][64];
    __shared__ float Bs[16][64];
    int wf = blk[0];
    int tid = threadIdx.x;
    int tx = tid & 15, ty = tid >> 4;
    int row0 = blockIdx.y * 64, col0 = blockIdx.x * 64;
    float acc[4][4] = {};
    int ar = tid >> 2, ac4 = tid & 3;
    int br = tid >> 4, bc4 = tid & 15;

    for (int kb = 0; kb < K; kb += 16) {
        {
            uint2 u = *(const uint2*)(A + (size_t)(row0 + ar) * K + kb + ac4 * 4);
            float a0, a1, a2, a3;
            unpack2(u.x, a0, a1); unpack2(u.y, a2, a3);
            As[ac4 * 4 + 0][ar] = a0; As[ac4 * 4 + 1][ar] = a1;
            As[ac4 * 4 + 2][ar] = a2; As[ac4 * 4 + 3][ar] = a3;
        }
        {
            size_t off = woff + (size_t)(kb + br) * ldw + col0 + bc4 * 4;
            if (wf) {
                float4 u = *(const float4*)((const float*)W + off);
                Bs[br][bc4 * 4 + 0] = u.x; Bs[br][bc4 * 4 + 1] = u.y;
                Bs[br][bc4 * 4 + 2] = u.z; Bs[br][bc4 * 4 + 3] = u.w;
            } else {
                uint2 u = *(const uint2*)((const u16*)W + off);
                float b0, b1, b2, b3;
                unpack2(u.x, b0, b1); unpack2(u.y, b2, b3);
                Bs[br][bc4 * 4 + 0] = b0; Bs[br][bc4 * 4 + 1] = b1;
                Bs[br][bc4 * 4 + 2] = b2; Bs[br][bc4 * 4 + 3] = b3;
            }
        }
        __syncthreads();
#pragma unroll
        for (int kk = 0; kk < 16; kk++) {
            float4 a = *(const float4*)&As[kk][ty * 4];
            float4 b = *(const float4*)&Bs[kk][tx * 4];
            float av[4] = {a.x, a.y, a.z, a.w};
            float bv[4] = {b.x, b.y, b.z, b.w};
#pragma unroll
            for (int i = 0; i < 4; i++)
#pragma unroll
                for (int j = 0; j < 4; j++)
                    acc[i][j] += av[i] * bv[j];
        }
        __syncthreads();
    }

#pragma unroll
    for (int i = 0; i < 4; i++) {
        int m = row0 + ty * 4 + i;
#pragma unroll
        for (int j = 0; j < 4; j++) {
            int n = col0 + tx * 4 + j;
            float v = acc[i][j];
            if (flags & 1) v += wget(bias, boff + n, wf);
            if (flags & 2) v = 0.5f * v * (1.0f + erff(v * 0.70710678118654752f));
            size_t idx = coff + (size_t)m * N + n;
            if (tcmode == 0) {
                ((float*)Cv)[idx] += v;
            } else if (tcmode == 1) {
                ((u16*)Cv)[idx] = f2bf(v);
            } else {
                if (wf) ((float*)Cv)[idx] += v;
                else { u16* p = (u16*)Cv; p[idx] = f2bf(v + bf2f(p[idx])); }
            }
        }
    }
}

// ---------------- masked attention, strided (single sample) ----------------
// Q/K/V/AO bf16 with row strides; head offset = blockIdx.y*96 into each row.
// Mask matches ref: invalid -> -1e30, softmax over ALL keys (fully-masked -> uniform).
#define TI 4
__global__ __launch_bounds__(256) void attn_kernel(const u16* __restrict__ Q,
                                                   const u16* __restrict__ K,
                                                   const u16* __restrict__ V,
                                                   u16* __restrict__ AO,
                                                   int ldq, int ldk, int ldv, int ldo,
                                                   const int* __restrict__ blk,
                                                   int bidx, int Lk, int is_self) {
    int hoff = blockIdx.y * HDIM;
    int i0 = blockIdx.x * TI;
    int tid = threadIdx.x;
    int us = blk[9];
    int elb = blk[1 + bidx];
    int el_q = elb * us;
    int el_k = is_self ? el_q : elb;

    __shared__ float qs[TI][HDIM];
    __shared__ float ss[TI][1024];
    __shared__ float po[2][TI][HDIM];
    __shared__ float denom[TI];

    for (int idx = tid; idx < TI * HDIM; idx += 256) {
        int ti = idx / HDIM, d = idx % HDIM;
        qs[ti][d] = bf2f(Q[(size_t)(i0 + ti) * ldq + hoff + d]);
    }
    __syncthreads();

    const float scale = 0.10206207261596576f;  // 1/sqrt(96)
    for (int j = tid; j < Lk; j += 256) {
        const u16* kr = K + (size_t)j * ldk + hoff;
        float sacc[TI] = {0.f, 0.f, 0.f, 0.f};
#pragma unroll
        for (int c = 0; c < 12; c++) {
            uint4 u = *(const uint4*)(kr + c * 8);
            float k0, k1, k2, k3, k4, k5, k6, k7;
            unpack2(u.x, k0, k1); unpack2(u.y, k2, k3);
            unpack2(u.z, k4, k5); unpack2(u.w, k6, k7);
            int base = c * 8;
#pragma unroll
            for (int ti = 0; ti < TI; ti++) {
                float4 qa = *(const float4*)&qs[ti][base];
                float4 qb = *(const float4*)&qs[ti][base + 4];
                sacc[ti] += qa.x * k0 + qa.y * k1 + qa.z * k2 + qa.w * k3 +
                            qb.x * k4 + qb.y * k5 + qb.z * k6 + qb.w * k7;
            }
        }
        bool vj = (j < el_k);
#pragma unroll
        for (int ti = 0; ti < TI; ti++) {
            bool vi = (i0 + ti) < el_q;
            ss[ti][j] = (vj && vi) ? sacc[ti] * scale : NEG_MASK;
        }
    }
    __syncthreads();

    {   // softmax: wave w owns row w
        int wid = tid >> 6, lane = tid & 63;
        float m = NEG_MASK;
        for (int j = lane; j < Lk; j += 64) m = fmaxf(m, ss[wid][j]);
#pragma unroll
        for (int off = 32; off > 0; off >>= 1) m = fmaxf(m, __shfl_xor(m, off, 64));
        float sum = 0.f;
        for (int j = lane; j < Lk; j += 64) {
            float e = __expf(ss[wid][j] - m);
            ss[wid][j] = e;
            sum += e;
        }
#pragma unroll
        for (int off = 32; off > 0; off >>= 1) sum += __shfl_xor(sum, off, 64);
        if (lane == 0) denom[wid] = fmaxf(sum, 1e-30f);
    }
    __syncthreads();

    if (tid < 2 * HDIM) {
        int d = tid % HDIM, part = tid / HDIM;
        int half = Lk >> 1;
        int j0 = part * half, j1 = j0 + half;
        float acc[TI] = {0.f, 0.f, 0.f, 0.f};
        for (int j = j0; j < j1; j++) {
            float v = bf2f(V[(size_t)j * ldv + hoff + d]);
#pragma unroll
            for (int ti = 0; ti < TI; ti++) acc[ti] += ss[ti][j] * v;
        }
#pragma unroll
        for (int ti = 0; ti < TI; ti++) po[part][ti][d] = acc[ti];
    }
    __syncthreads();

    for (int idx = tid; idx < TI * HDIM; idx += 256) {
        int ti = idx / HDIM, d = idx % HDIM;
        float o = (po[0][ti][d] + po[1][ti][d]) / denom[ti];
        AO[(size_t)(i0 + ti) * ldo + hoff + d] = f2bf(o);
    }
}

// ---------------- launcher ----------------
extern "C" void kernel_launch(void* const* d_in, const int* in_sizes, int n_in,
                              void* d_out, int out_size, void* d_ws, size_t ws_size,
                              hipStream_t stream) {
    const void* x    = d_in[0];
    const void* c    = d_in[1];
    const int* el    = (const int*)d_in[2];
    const int* us    = (const int*)d_in[3];
    const void* Wq1  = d_in[4];
    const void* Wkv1 = d_in[5];
    const void* Wo1  = d_in[6];
    const void* bo1  = d_in[7];
    const void* Wq2  = d_in[8];
    const void* Wkv2 = d_in[9];
    const void* Wo2  = d_in[10];
    const void* bo2  = d_in[11];
    const void* g1 = d_in[12]; const void* b1 = d_in[13];
    const void* g2 = d_in[14]; const void* b2 = d_in[15];
    const void* g4 = d_in[16]; const void* b4 = d_in[17];
    const void* gc = d_in[18]; const void* bc = d_in[19];
    const void* Wf1 = d_in[20]; const void* bf1 = d_in[21];
    const void* Wf2 = d_in[22]; const void* bf2 = d_in[23];

    const int B = 8, S = 512, L = 1024, C = EMBED;
    const int NX = B * L * C;               // 6,291,456
    const size_t RL = (size_t)L * C;        // 786432
    const size_t RS = (size_t)S * C;        // 393216

    char* ws = (char*)d_ws;
    int*  blk = (int*)ws;
    dim3 blkd(256);

    bool big = ws_size >= (size_t)33030208;

    detect_kernel<<<1, 64, 0, stream>>>((const u16*)x, el, us, blk);

    if (big) {
        // ws: blk 64 | X f32 24 MB | XN bf16 1.5 MB | P 6 MB   = 33,030,208 B
        float* X  = (float*)(ws + 64);
        u16*   XN = (u16*)(ws + 64 + 25165824);
        char*  P  = ws + 64 + 25165824 + 1572864;
        u16* Qb   = (u16*)P;                      // 1,572,864
        u16* KVb  = (u16*)(P + 1572864);          // 3,145,728
        u16* AOb  = (u16*)(P + 4718592);          // 1,572,864
        u16* CNb  = (u16*)P;                      //   786,432
        u16* KV2b = (u16*)(P + 786432);           // 1,572,864
        u16* Q2b  = (u16*)(P + 2359296);          // 1,572,864
        u16* AO2b = (u16*)(P + 3932160);          // 1,572,864
        u16* Hb   = (u16*)P;                      // 6,291,456

        wire_to_f32<<<(NX + 255) / 256, blkd, 0, stream>>>(x, 0, X, NX, blk);

        for (int b = 0; b < B; b++) {
            size_t ro = (size_t)b * RL;
            // self attention
            ln_kernel<<<L, blkd, 0, stream>>>(X, ro, 0, g1, b1, XN, blk);
            gemm_kernel<<<dim3(12, 16), blkd, 0, stream>>>(XN, Wq1, 0, C, nullptr, 0, Qb, 0, L, C, C, 0, 1, blk);
            gemm_kernel<<<dim3(24, 16), blkd, 0, stream>>>(XN, Wkv1, 0, 2 * C, nullptr, 0, KVb, 0, L, 2 * C, C, 0, 1, blk);
            attn_kernel<<<dim3(256, 8), blkd, 0, stream>>>(Qb, KVb, KVb + C, AOb, C, 2 * C, 2 * C, C, blk, b, L, 1);
            gemm_kernel<<<dim3(12, 16), blkd, 0, stream>>>(AOb, Wo1, 0, C, bo1, 0, X, ro, L, C, C, 1, 0, blk);
            // cross attention
            ln_kernel<<<L, blkd, 0, stream>>>(X, ro, 0, g2, b2, XN, blk);
            ln_kernel<<<S, blkd, 0, stream>>>(c, (size_t)b * RS, 2, gc, bc, CNb, blk);
            gemm_kernel<<<dim3(24, 8), blkd, 0, stream>>>(CNb, Wkv2, 0, 2 * C, nullptr, 0, KV2b, 0, S, 2 * C, C, 0, 1, blk);
            gemm_kernel<<<dim3(12, 16), blkd, 0, stream>>>(XN, Wq2, 0, C, nullptr, 0, Q2b, 0, L, C, C, 0, 1, blk);
            attn_kernel<<<dim3(256, 8), blkd, 0, stream>>>(Q2b, KV2b, KV2b + C, AO2b, C, 2 * C, 2 * C, C, blk, b, S, 0);
            gemm_kernel<<<dim3(12, 16), blkd, 0, stream>>>(AO2b, Wo2, 0, C, bo2, 0, X, ro, L, C, C, 1, 0, blk);
            // ffn
            ln_kernel<<<L, blkd, 0, stream>>>(X, ro, 0, g4, b4, XN, blk);
            gemm_kernel<<<dim3(48, 16), blkd, 0, stream>>>(XN, Wf1, 0, 4 * C, bf1, 0, Hb, 0, L, 4 * C, C, 1 | 2, 1, blk);
            gemm_kernel<<<dim3(12, 16), blkd, 0, stream>>>(Hb, Wf2, 0, C, bf2, 0, X, ro, L, C, 4 * C, 1, 0, blk);
        }
        f32_to_out<<<(NX + 255) / 256, blkd, 0, stream>>>(X, d_out, 0, NX, blk);
    } else {
        // micro: residual lives in d_out in WIRE dtype the whole time.
        // ws: blk 64 | XN 1.5 MB | CN 0.75 MB | P2 1.5 MB = 3,932,224 B
        u16*  XN  = (u16*)(ws + 64);
        u16*  CNb = (u16*)(ws + 64 + 1572864);
        char* P2  = ws + 64 + 1572864 + 786432;
        u16* Qp  = (u16*)P2;                    // 393,216
        u16* Kp  = (u16*)(P2 + 393216);         // 393,216
        u16* Vp  = (u16*)(P2 + 786432);         // 393,216
        u16* AOp = (u16*)(P2 + 1179648);        // 393,216
        u16* Hc  = (u16*)P2;                    // 1,572,864 (FFN phase)

        wire_copy<<<(NX + 255) / 256, blkd, 0, stream>>>(x, d_out, NX, blk);

        for (int b = 0; b < B; b++) {
            size_t ro = (size_t)b * RL;

            // ---- self attention (head pairs) ----
            ln_kernel<<<L, blkd, 0, stream>>>(d_out, ro, 2, g1, b1, XN, blk);
            for (int p = 0; p < 4; p++) {
                int h = 2 * p;
                gemm_kernel<<<dim3(3, 16), blkd, 0, stream>>>(XN, Wq1, (size_t)h * 96, C, nullptr, 0, Qp, 0, L, 192, C, 0, 1, blk);
                gemm_kernel<<<dim3(3, 16), blkd, 0, stream>>>(XN, Wkv1, (size_t)h * 96, 2 * C, nullptr, 0, Kp, 0, L, 192, C, 0, 1, blk);
                gemm_kernel<<<dim3(3, 16), blkd, 0, stream>>>(XN, Wkv1, (size_t)(C + h * 96), 2 * C, nullptr, 0, Vp, 0, L, 192, C, 0, 1, blk);
                attn_kernel<<<dim3(256, 2), blkd, 0, stream>>>(Qp, Kp, Vp, AOp, 192, 192, 192, 192, blk, b, L, 1);
                gemm_kernel<<<dim3(12, 16), blkd, 0, stream>>>(AOp, Wo1, (size_t)h * 96 * C, C, bo1, 0, d_out, ro, L, C, 192, (p == 0) ? 1 : 0, 3, blk);
            }
            // ---- cross attention ----
            ln_kernel<<<L, blkd, 0, stream>>>(d_out, ro, 2, g2, b2, XN, blk);
            ln_kernel<<<S, blkd, 0, stream>>>(c, (size_t)b * RS, 2, gc, bc, CNb, blk);
            for (int p = 0; p < 4; p++) {
                int h = 2 * p;
                gemm_kernel<<<dim3(3, 16), blkd, 0, stream>>>(XN, Wq2, (size_t)h * 96, C, nullptr, 0, Qp, 0, L, 192, C, 0, 1, blk);
                gemm_kernel<<<dim3(3, 8), blkd, 0, stream>>>(CNb, Wkv2, (size_t)h * 96, 2 * C, nullptr, 0, Kp, 0, S, 192, C, 0, 1, blk);
                gemm_kernel<<<dim3(3, 8), blkd, 0, stream>>>(CNb, Wkv2, (size_t)(C + h * 96), 2 * C, nullptr, 0, Vp, 0, S, 192, C, 0, 1, blk);
                attn_kernel<<<dim3(256, 2), blkd, 0, stream>>>(Qp, Kp, Vp, AOp, 192, 192, 192, 192, blk, b, S, 0);
                gemm_kernel<<<dim3(12, 16), blkd, 0, stream>>>(AOp, Wo2, (size_t)h * 96 * C, C, bo2, 0, d_out, ro, L, C, 192, (p == 0) ? 1 : 0, 3, blk);
            }
            // ---- FFN (K-chunked) ----
            ln_kernel<<<L, blkd, 0, stream>>>(d_out, ro, 2, g4, b4, XN, blk);
            for (int ch = 0; ch < 4; ch++) {
                gemm_kernel<<<dim3(12, 16), blkd, 0, stream>>>(XN, Wf1, (size_t)ch * C, 4 * C, bf1, ch * C, Hc, 0, L, C, C, 1 | 2, 1, blk);
                gemm_kernel<<<dim3(12, 16), blkd, 0, stream>>>(Hc, Wf2, (size_t)ch * C * C, C, bf2, 0, d_out, ro, L, C, C, (ch == 0) ? 1 : 0, 3, blk);
            }
        }
    }
}

// Round 7
// 4999.288 us; speedup vs baseline: 3.6113x; 3.6113x over previous
//
#include <hip/hip_runtime.h>
#include <math.h>

#define EMBED 768
#define HEADS 8
#define HDIM  96
#define NEG_MASK (-1.0e30f)

typedef unsigned short u16;
typedef unsigned int   u32;

__device__ __forceinline__ float bf2f(u16 u) {
    return __uint_as_float(((u32)u) << 16);
}
__device__ __forceinline__ u16 f2bf(float f) {
    u32 x = __float_as_uint(f);
    u32 r = (x + 0x7fffu + ((x >> 16) & 1u)) >> 16;
    return (u16)r;
}
__device__ __forceinline__ void unpack2(u32 w, float& lo, float& hi) {
    lo = __uint_as_float(w << 16);
    hi = __uint_as_float(w & 0xffff0000u);
}
__device__ __forceinline__ float wget(const void* p, size_t i, int wf) {
    return wf ? ((const float*)p)[i] : bf2f(((const u16*)p)[i]);
}

// ---------------- detection: one wave, no barriers ----------------
// blk[0]=wf (1 = wire f32), blk[1..8]=effect_lengths, blk[9]=us_rate
__global__ __launch_bounds__(64) void detect_kernel(const u16* __restrict__ x,
                                                    const int* __restrict__ el,
                                                    const int* __restrict__ usp,
                                                    int* __restrict__ blk) {
    int lane = threadIdx.x;
    int cnt = 0;
    for (int i = lane; i < 4096; i += 64) {
        u32 e = (x[i] >> 7) & 0xFFu;
        if (e >= 0xC0u) cnt++;
    }
#pragma unroll
    for (int off = 32; off > 0; off >>= 1) cnt += __shfl_xor(cnt, off, 64);
    if (lane == 0) {
        blk[0] = (cnt > 32) ? 1 : 0;
        bool i64 = (el[1] == 0) && (el[3] == 0) && (el[5] == 0) && (el[7] == 0);
        for (int b = 0; b < 8; b++) blk[1 + b] = i64 ? el[2 * b] : el[b];
        blk[9] = usp[0];
    }
}

// ---------------- copies ----------------
__global__ void wire_to_f32(const void* __restrict__ in, size_t ioff,
                            float* __restrict__ out, int n,
                            const int* __restrict__ blk) {
    int i = blockIdx.x * blockDim.x + threadIdx.x;
    int wf = blk[0];
    if (i < n) out[i] = wget(in, ioff + (size_t)i, wf);
}
__global__ void wire_copy(const void* __restrict__ in, void* __restrict__ out,
                          int n, const int* __restrict__ blk) {
    int i = blockIdx.x * blockDim.x + threadIdx.x;
    int wf = blk[0];
    if (i < n) {
        if (wf) ((float*)out)[i] = ((const float*)in)[i];
        else    ((u16*)out)[i]   = ((const u16*)in)[i];
    }
}
__global__ void f32_to_out(const float* __restrict__ in, void* __restrict__ out,
                           size_t ooff, int n, const int* __restrict__ blk) {
    int i = blockIdx.x * blockDim.x + threadIdx.x;
    int wf = blk[0];
    if (i < n) {
        if (wf) ((float*)out)[ooff + i] = in[i];
        else    ((u16*)out)[ooff + i]   = f2bf(in[i]);
    }
}

// ---------------- LayerNorm (768 cols, 1 row/block, 256 thr) ----------------
// sel 0: in = f32 buffer; sel 2: in = wire-dtype buffer. Output bf16.
__global__ __launch_bounds__(256) void ln_kernel(const void* __restrict__ in,
                                                 size_t ioff, int sel,
                                                 const void* __restrict__ g,
                                                 const void* __restrict__ b,
                                                 u16* __restrict__ out,
                                                 const int* __restrict__ blk) {
    int wf = blk[0];
    int row = blockIdx.x, tid = threadIdx.x;
    size_t base = ioff + (size_t)row * EMBED;
    float v[3];
#pragma unroll
    for (int e = 0; e < 3; e++) {
        size_t idx = base + tid + e * 256;
        v[e] = (sel == 0) ? ((const float*)in)[idx] : wget(in, idx, wf);
    }
    float s = v[0] + v[1] + v[2];
    float q = v[0] * v[0] + v[1] * v[1] + v[2] * v[2];
#pragma unroll
    for (int off = 32; off > 0; off >>= 1) {
        s += __shfl_xor(s, off, 64);
        q += __shfl_xor(q, off, 64);
    }
    __shared__ float sb[8];
    int wid = tid >> 6, lane = tid & 63;
    if (lane == 0) { sb[wid] = s; sb[4 + wid] = q; }
    __syncthreads();
    if (tid == 0) {
        sb[0] = sb[0] + sb[1] + sb[2] + sb[3];
        sb[4] = sb[4] + sb[5] + sb[6] + sb[7];
    }
    __syncthreads();
    float mean = sb[0] * (1.0f / EMBED);
    float var  = sb[4] * (1.0f / EMBED) - mean * mean;
    float rs   = rsqrtf(var + 1e-5f);
    size_t obase = (size_t)row * EMBED;
#pragma unroll
    for (int e = 0; e < 3; e++) {
        int col = tid + e * 256;
        out[obase + col] = f2bf((v[e] - mean) * rs * wget(g, col, wf) + wget(b, col, wf));
    }
}

// ---------------- GEMM: C[M,N] (+)= op(A[M,K] @ W[woff.., ldw] (+bias[boff..]) (gelu))
// A bf16. W/bias wire dtype. tcmode: 0 = f32 accumulate; 1 = bf16 store; 3 = wire accumulate.
// flags: 1 bias, 2 exact GELU. M%64==0, N%64==0, K%16==0.
__global__ __launch_bounds__(256) void gemm_kernel(const u16* __restrict__ A,
                                                   const void* __restrict__ W,
                                                   size_t woff, int ldw,
                                                   const void* __restrict__ bias, int boff,
                                                   void* __restrict__ Cv, size_t coff,
                                                   int M, int N, int K, int flags,
                                                   int tcmode, const int* __restrict__ blk) {
    __shared__ float As[16][64];
    __shared__ float Bs[16][64];
    int wf = blk[0];
    int tid = threadIdx.x;
    int tx = tid & 15, ty = tid >> 4;
    int row0 = blockIdx.y * 64, col0 = blockIdx.x * 64;
    float acc[4][4] = {};
    int ar = tid >> 2, ac4 = tid & 3;
    int br = tid >> 4, bc4 = tid & 15;

    for (int kb = 0; kb < K; kb += 16) {
        {
            uint2 u = *(const uint2*)(A + (size_t)(row0 + ar) * K + kb + ac4 * 4);
            float a0, a1, a2, a3;
            unpack2(u.x, a0, a1); unpack2(u.y, a2, a3);
            As[ac4 * 4 + 0][ar] = a0; As[ac4 * 4 + 1][ar] = a1;
            As[ac4 * 4 + 2][ar] = a2; As[ac4 * 4 + 3][ar] = a3;
        }
        {
            size_t off = woff + (size_t)(kb + br) * ldw + col0 + bc4 * 4;
            if (wf) {
                float4 u = *(const float4*)((const float*)W + off);
                Bs[br][bc4 * 4 + 0] = u.x; Bs[br][bc4 * 4 + 1] = u.y;
                Bs[br][bc4 * 4 + 2] = u.z; Bs[br][bc4 * 4 + 3] = u.w;
            } else {
                uint2 u = *(const uint2*)((const u16*)W + off);
                float b0, b1, b2, b3;
                unpack2(u.x, b0, b1); unpack2(u.y, b2, b3);
                Bs[br][bc4 * 4 + 0] = b0; Bs[br][bc4 * 4 + 1] = b1;
                Bs[br][bc4 * 4 + 2] = b2; Bs[br][bc4 * 4 + 3] = b3;
            }
        }
        __syncthreads();
#pragma unroll
        for (int kk = 0; kk < 16; kk++) {
            float4 a = *(const float4*)&As[kk][ty * 4];
            float4 b = *(const float4*)&Bs[kk][tx * 4];
            float av[4] = {a.x, a.y, a.z, a.w};
            float bv[4] = {b.x, b.y, b.z, b.w};
#pragma unroll
            for (int i = 0; i < 4; i++)
#pragma unroll
                for (int j = 0; j < 4; j++)
                    acc[i][j] += av[i] * bv[j];
        }
        __syncthreads();
    }

#pragma unroll
    for (int i = 0; i < 4; i++) {
        int m = row0 + ty * 4 + i;
#pragma unroll
        for (int j = 0; j < 4; j++) {
            int n = col0 + tx * 4 + j;
            float v = acc[i][j];
            if (flags & 1) v += wget(bias, boff + n, wf);
            if (flags & 2) v = 0.5f * v * (1.0f + erff(v * 0.70710678118654752f));
            size_t idx = coff + (size_t)m * N + n;
            if (tcmode == 0) {
                ((float*)Cv)[idx] += v;
            } else if (tcmode == 1) {
                ((u16*)Cv)[idx] = f2bf(v);
            } else {
                if (wf) ((float*)Cv)[idx] += v;
                else { u16* p = (u16*)Cv; p[idx] = f2bf(v + bf2f(p[idx])); }
            }
        }
    }
}

// ---------------- flash attention: 16 q-rows/block, 64-key LDS tiles ----------------
// Q/K/V/AO bf16, row strides ld*; per-sample element strides qss/kss/oss used when
// bfix < 0 (batched, sample = blockIdx.z); else single sample bfix, strides ignored.
// Mask matches ref: invalid -> -1e30, softmax over ALL keys (fully-masked -> uniform).
#define ATI 16
#define AKT 64
__global__ __launch_bounds__(256) void attn_kernel(const u16* __restrict__ Q,
                                                   const u16* __restrict__ K,
                                                   const u16* __restrict__ V,
                                                   u16* __restrict__ AO,
                                                   int ldq, int ldk, int ldv, int ldo,
                                                   size_t qss, size_t kss, size_t oss,
                                                   const int* __restrict__ blk,
                                                   int bfix, int Lk, int is_self) {
    int bz   = (bfix < 0) ? blockIdx.z : 0;
    int bidx = (bfix < 0) ? blockIdx.z : bfix;
    const u16* Qp = Q + (size_t)bz * qss;
    const u16* Kp = K + (size_t)bz * kss;
    const u16* Vp = V + (size_t)bz * kss;
    u16* AOp = AO + (size_t)bz * oss;

    int hoff = blockIdx.y * HDIM;
    int i0 = blockIdx.x * ATI;
    int tid = threadIdx.x;
    int elb = blk[1 + bidx];
    int el_q = elb * blk[9];
    int el_k = is_self ? el_q : elb;

    __shared__ float qs[ATI][100];          // [r][d]
    __shared__ float kt[HDIM][AKT + 4];     // [d][k]
    __shared__ float vt[HDIM][AKT + 4];     // [d][k] (i.e. V^T)
    __shared__ float ss[ATI][AKT + 4];      // scores / probs
    __shared__ float sm[ATI][16];           // per-(row, tx) partial max
    __shared__ float mrow[ATI], lrow[ATI], arow[ATI];

    if (tid < 192) {
        int r = tid / 12, c = tid % 12;
        uint4 u = *(const uint4*)(Qp + (size_t)(i0 + r) * ldq + hoff + c * 8);
        float f0, f1, f2, f3, f4, f5, f6, f7;
        unpack2(u.x, f0, f1); unpack2(u.y, f2, f3);
        unpack2(u.z, f4, f5); unpack2(u.w, f6, f7);
        float* qp = &qs[r][c * 8];
        qp[0] = f0; qp[1] = f1; qp[2] = f2; qp[3] = f3;
        qp[4] = f4; qp[5] = f5; qp[6] = f6; qp[7] = f7;
    }
    if (tid < ATI) { mrow[tid] = NEG_MASK; lrow[tid] = 0.f; }
    float o0 = 0, o1 = 0, o2 = 0, o3 = 0, o4 = 0, o5 = 0;
    int rs = tid >> 4, tx = tid & 15;
    __syncthreads();

    const float scale = 0.10206207261596576f;  // 1/sqrt(96)
    for (int kt0 = 0; kt0 < Lk; kt0 += AKT) {
        // ---- stage K/V tile transposed into LDS ----
#pragma unroll
        for (int t = 0; t < 3; t++) {
            int idx = tid + t * 256;
            int j = idx / 12, c = idx % 12;
            int d0 = c * 8;
            float f0, f1, f2, f3, f4, f5, f6, f7;
            uint4 u = *(const uint4*)(Kp + (size_t)(kt0 + j) * ldk + hoff + c * 8);
            unpack2(u.x, f0, f1); unpack2(u.y, f2, f3);
            unpack2(u.z, f4, f5); unpack2(u.w, f6, f7);
            kt[d0 + 0][j] = f0; kt[d0 + 1][j] = f1; kt[d0 + 2][j] = f2; kt[d0 + 3][j] = f3;
            kt[d0 + 4][j] = f4; kt[d0 + 5][j] = f5; kt[d0 + 6][j] = f6; kt[d0 + 7][j] = f7;
            uint4 w = *(const uint4*)(Vp + (size_t)(kt0 + j) * ldv + hoff + c * 8);
            unpack2(w.x, f0, f1); unpack2(w.y, f2, f3);
            unpack2(w.z, f4, f5); unpack2(w.w, f6, f7);
            vt[d0 + 0][j] = f0; vt[d0 + 1][j] = f1; vt[d0 + 2][j] = f2; vt[d0 + 3][j] = f3;
            vt[d0 + 4][j] = f4; vt[d0 + 5][j] = f5; vt[d0 + 6][j] = f6; vt[d0 + 7][j] = f7;
        }
        __syncthreads();

        // ---- scores: thread (rs, tx) -> keys 4tx..4tx+3 ----
        float s0 = 0, s1 = 0, s2 = 0, s3 = 0;
#pragma unroll
        for (int d = 0; d < HDIM; d += 4) {
            float4 q = *(const float4*)&qs[rs][d];
            float4 k0 = *(const float4*)&kt[d + 0][tx * 4];
            s0 += q.x * k0.x; s1 += q.x * k0.y; s2 += q.x * k0.z; s3 += q.x * k0.w;
            float4 k1 = *(const float4*)&kt[d + 1][tx * 4];
            s0 += q.y * k1.x; s1 += q.y * k1.y; s2 += q.y * k1.z; s3 += q.y * k1.w;
            float4 k2 = *(const float4*)&kt[d + 2][tx * 4];
            s0 += q.z * k2.x; s1 += q.z * k2.y; s2 += q.z * k2.z; s3 += q.z * k2.w;
            float4 k3 = *(const float4*)&kt[d + 3][tx * 4];
            s0 += q.w * k3.x; s1 += q.w * k3.y; s2 += q.w * k3.z; s3 += q.w * k3.w;
        }
        bool vi = (i0 + rs) < el_q;
        int kb = kt0 + tx * 4;
        s0 = (vi && (kb + 0) < el_k) ? s0 * scale : NEG_MASK;
        s1 = (vi && (kb + 1) < el_k) ? s1 * scale : NEG_MASK;
        s2 = (vi && (kb + 2) < el_k) ? s2 * scale : NEG_MASK;
        s3 = (vi && (kb + 3) < el_k) ? s3 * scale : NEG_MASK;
        ss[rs][tx * 4 + 0] = s0; ss[rs][tx * 4 + 1] = s1;
        ss[rs][tx * 4 + 2] = s2; ss[rs][tx * 4 + 3] = s3;
        sm[rs][tx] = fmaxf(fmaxf(s0, s1), fmaxf(s2, s3));
        __syncthreads();

        // ---- running-max update (threads 0..15) ----
        if (tid < ATI) {
            int r = tid;
            float mo = mrow[r];
            float4 a = *(const float4*)&sm[r][0];
            float4 b = *(const float4*)&sm[r][4];
            float4 c = *(const float4*)&sm[r][8];
            float4 d = *(const float4*)&sm[r][12];
            float mt = fmaxf(mo,
                fmaxf(fmaxf(fmaxf(fmaxf(a.x, a.y), fmaxf(a.z, a.w)),
                            fmaxf(fmaxf(b.x, b.y), fmaxf(b.z, b.w))),
                      fmaxf(fmaxf(fmaxf(c.x, c.y), fmaxf(c.z, c.w)),
                            fmaxf(fmaxf(d.x, d.y), fmaxf(d.z, d.w)))));
            float alpha = __expf(mo - mt);   // both -1e30 -> 1; -1e30 vs real -> 0
            mrow[r] = mt; arow[r] = alpha;
            lrow[r] *= alpha;
        }
        __syncthreads();

        // ---- PV with fused exp: thread (rs, tx) -> cols tx*6..+5 ----
        float mt = mrow[rs];
        float al = arow[rs];
        o0 *= al; o1 *= al; o2 *= al; o3 *= al; o4 *= al; o5 *= al;
        float lsum = 0.f;
        int c0 = tx * 6;
#pragma unroll
        for (int k = 0; k < AKT; k += 4) {
            float4 sv = *(const float4*)&ss[rs][k];
            float p0 = __expf(sv.x - mt);
            float p1 = __expf(sv.y - mt);
            float p2 = __expf(sv.z - mt);
            float p3 = __expf(sv.w - mt);
            lsum += p0 + p1 + p2 + p3;
            float4 v0 = *(const float4*)&vt[c0 + 0][k];
            o0 += p0 * v0.x + p1 * v0.y + p2 * v0.z + p3 * v0.w;
            float4 v1 = *(const float4*)&vt[c0 + 1][k];
            o1 += p0 * v1.x + p1 * v1.y + p2 * v1.z + p3 * v1.w;
            float4 v2 = *(const float4*)&vt[c0 + 2][k];
            o2 += p0 * v2.x + p1 * v2.y + p2 * v2.z + p3 * v2.w;
            float4 v3 = *(const float4*)&vt[c0 + 3][k];
            o3 += p0 * v3.x + p1 * v3.y + p2 * v3.z + p3 * v3.w;
            float4 v4 = *(const float4*)&vt[c0 + 4][k];
            o4 += p0 * v4.x + p1 * v4.y + p2 * v4.z + p3 * v4.w;
            float4 v5 = *(const float4*)&vt[c0 + 5][k];
            o5 += p0 * v5.x + p1 * v5.y + p2 * v5.z + p3 * v5.w;
        }
        if (tx == 0) lrow[rs] += lsum;
        __syncthreads();
    }

    float inv = 1.0f / lrow[rs];
    size_t ob = (size_t)(i0 + rs) * ldo + hoff + tx * 6;
    AOp[ob + 0] = f2bf(o0 * inv); AOp[ob + 1] = f2bf(o1 * inv);
    AOp[ob + 2] = f2bf(o2 * inv); AOp[ob + 3] = f2bf(o3 * inv);
    AOp[ob + 4] = f2bf(o4 * inv); AOp[ob + 5] = f2bf(o5 * inv);
}

// ---------------- launcher ----------------
extern "C" void kernel_launch(void* const* d_in, const int* in_sizes, int n_in,
                              void* d_out, int out_size, void* d_ws, size_t ws_size,
                              hipStream_t stream) {
    const void* x    = d_in[0];
    const void* c    = d_in[1];
    const int* el    = (const int*)d_in[2];
    const int* us    = (const int*)d_in[3];
    const void* Wq1  = d_in[4];
    const void* Wkv1 = d_in[5];
    const void* Wo1  = d_in[6];
    const void* bo1  = d_in[7];
    const void* Wq2  = d_in[8];
    const void* Wkv2 = d_in[9];
    const void* Wo2  = d_in[10];
    const void* bo2  = d_in[11];
    const void* g1 = d_in[12]; const void* b1 = d_in[13];
    const void* g2 = d_in[14]; const void* b2 = d_in[15];
    const void* g4 = d_in[16]; const void* b4 = d_in[17];
    const void* gc = d_in[18]; const void* bc = d_in[19];
    const void* Wf1 = d_in[20]; const void* bf1 = d_in[21];
    const void* Wf2 = d_in[22]; const void* bf2 = d_in[23];

    const int B = 8, S = 512, L = 1024, C = EMBED;
    const int NX = B * L * C;               // 6,291,456
    const size_t RL = (size_t)L * C;        // 786432
    const size_t RS = (size_t)S * C;        // 393216

    char* ws = (char*)d_ws;
    int*  blk = (int*)ws;
    dim3 blkd(256);

    bool tierA = ws_size >= (size_t)88080448;
    bool tierB = !tierA && ws_size >= (size_t)33030208;

    detect_kernel<<<1, 64, 0, stream>>>((const u16*)x, el, us, blk);

    if (tierA) {
        // ws: blk 64 | X f32 24MB | XN bf16 12MB | pool 48MB = 88,080,448 B
        float* X  = (float*)(ws + 64);
        u16*   XN = (u16*)(ws + 64 + 25165824);
        char*  P  = ws + 64 + 25165824 + 12582912;
        u16* Qb   = (u16*)P;                      // 12,582,912
        u16* KVb  = (u16*)(P + 12582912);         // 25,165,824
        u16* AOb  = (u16*)(P + 37748736);         // 12,582,912
        u16* CNb  = (u16*)P;                      //  6,291,456
        u16* KV2b = (u16*)(P + 6291456);          // 12,582,912
        u16* Q2b  = (u16*)(P + 18874368);         // 12,582,912
        u16* AO2b = (u16*)(P + 31457280);         // 12,582,912
        u16* Hb   = (u16*)P;                      // 37,748,736

        wire_to_f32<<<(NX + 255) / 256, blkd, 0, stream>>>(x, 0, X, NX, blk);

        // ---- self attention (batched M = 8192) ----
        ln_kernel<<<B * L, blkd, 0, stream>>>(X, 0, 0, g1, b1, XN, blk);
        gemm_kernel<<<dim3(12, 128), blkd, 0, stream>>>(XN, Wq1, 0, C, nullptr, 0, Qb, 0, B * L, C, C, 0, 1, blk);
        gemm_kernel<<<dim3(24, 128), blkd, 0, stream>>>(XN, Wkv1, 0, 2 * C, nullptr, 0, KVb, 0, B * L, 2 * C, C, 0, 1, blk);
        attn_kernel<<<dim3(64, 8, 8), blkd, 0, stream>>>(Qb, KVb, KVb + C, AOb, C, 2 * C, 2 * C, C,
                                                         RL, (size_t)L * 2 * C, RL, blk, -1, L, 1);
        gemm_kernel<<<dim3(12, 128), blkd, 0, stream>>>(AOb, Wo1, 0, C, bo1, 0, X, 0, B * L, C, C, 1, 0, blk);

        // ---- cross attention ----
        ln_kernel<<<B * L, blkd, 0, stream>>>(X, 0, 0, g2, b2, XN, blk);
        ln_kernel<<<B * S, blkd, 0, stream>>>(c, 0, 2, gc, bc, CNb, blk);
        gemm_kernel<<<dim3(24, 64), blkd, 0, stream>>>(CNb, Wkv2, 0, 2 * C, nullptr, 0, KV2b, 0, B * S, 2 * C, C, 0, 1, blk);
        gemm_kernel<<<dim3(12, 128), blkd, 0, stream>>>(XN, Wq2, 0, C, nullptr, 0, Q2b, 0, B * L, C, C, 0, 1, blk);
        attn_kernel<<<dim3(64, 8, 8), blkd, 0, stream>>>(Q2b, KV2b, KV2b + C, AO2b, C, 2 * C, 2 * C, C,
                                                         RL, (size_t)S * 2 * C, RL, blk, -1, S, 0);
        gemm_kernel<<<dim3(12, 128), blkd, 0, stream>>>(AO2b, Wo2, 0, C, bo2, 0, X, 0, B * L, C, C, 1, 0, blk);

        // ---- FFN ----
        ln_kernel<<<B * L, blkd, 0, stream>>>(X, 0, 0, g4, b4, XN, blk);
        gemm_kernel<<<dim3(48, 128), blkd, 0, stream>>>(XN, Wf1, 0, 4 * C, bf1, 0, Hb, 0, B * L, 4 * C, C, 1 | 2, 1, blk);
        gemm_kernel<<<dim3(12, 128), blkd, 0, stream>>>(Hb, Wf2, 0, C, bf2, 0, X, 0, B * L, C, 4 * C, 1, 0, blk);

        f32_to_out<<<(NX + 255) / 256, blkd, 0, stream>>>(X, d_out, 0, NX, blk);
    } else if (tierB) {
        // round-6 per-sample structure, new attn kernel
        float* X  = (float*)(ws + 64);
        u16*   XN = (u16*)(ws + 64 + 25165824);
        char*  P  = ws + 64 + 25165824 + 1572864;
        u16* Qb   = (u16*)P;
        u16* KVb  = (u16*)(P + 1572864);
        u16* AOb  = (u16*)(P + 4718592);
        u16* CNb  = (u16*)P;
        u16* KV2b = (u16*)(P + 786432);
        u16* Q2b  = (u16*)(P + 2359296);
        u16* AO2b = (u16*)(P + 3932160);
        u16* Hb   = (u16*)P;

        wire_to_f32<<<(NX + 255) / 256, blkd, 0, stream>>>(x, 0, X, NX, blk);

        for (int b = 0; b < B; b++) {
            size_t ro = (size_t)b * RL;
            ln_kernel<<<L, blkd, 0, stream>>>(X, ro, 0, g1, b1, XN, blk);
            gemm_kernel<<<dim3(12, 16), blkd, 0, stream>>>(XN, Wq1, 0, C, nullptr, 0, Qb, 0, L, C, C, 0, 1, blk);
            gemm_kernel<<<dim3(24, 16), blkd, 0, stream>>>(XN, Wkv1, 0, 2 * C, nullptr, 0, KVb, 0, L, 2 * C, C, 0, 1, blk);
            attn_kernel<<<dim3(64, 8), blkd, 0, stream>>>(Qb, KVb, KVb + C, AOb, C, 2 * C, 2 * C, C, 0, 0, 0, blk, b, L, 1);
            gemm_kernel<<<dim3(12, 16), blkd, 0, stream>>>(AOb, Wo1, 0, C, bo1, 0, X, ro, L, C, C, 1, 0, blk);

            ln_kernel<<<L, blkd, 0, stream>>>(X, ro, 0, g2, b2, XN, blk);
            ln_kernel<<<S, blkd, 0, stream>>>(c, (size_t)b * RS, 2, gc, bc, CNb, blk);
            gemm_kernel<<<dim3(24, 8), blkd, 0, stream>>>(CNb, Wkv2, 0, 2 * C, nullptr, 0, KV2b, 0, S, 2 * C, C, 0, 1, blk);
            gemm_kernel<<<dim3(12, 16), blkd, 0, stream>>>(XN, Wq2, 0, C, nullptr, 0, Q2b, 0, L, C, C, 0, 1, blk);
            attn_kernel<<<dim3(64, 8), blkd, 0, stream>>>(Q2b, KV2b, KV2b + C, AO2b, C, 2 * C, 2 * C, C, 0, 0, 0, blk, b, S, 0);
            gemm_kernel<<<dim3(12, 16), blkd, 0, stream>>>(AO2b, Wo2, 0, C, bo2, 0, X, ro, L, C, C, 1, 0, blk);

            ln_kernel<<<L, blkd, 0, stream>>>(X, ro, 0, g4, b4, XN, blk);
            gemm_kernel<<<dim3(48, 16), blkd, 0, stream>>>(XN, Wf1, 0, 4 * C, bf1, 0, Hb, 0, L, 4 * C, C, 1 | 2, 1, blk);
            gemm_kernel<<<dim3(12, 16), blkd, 0, stream>>>(Hb, Wf2, 0, C, bf2, 0, X, ro, L, C, 4 * C, 1, 0, blk);
        }
        f32_to_out<<<(NX + 255) / 256, blkd, 0, stream>>>(X, d_out, 0, NX, blk);
    } else {
        // micro: residual lives in d_out in WIRE dtype.
        u16*  XN  = (u16*)(ws + 64);
        u16*  CNb = (u16*)(ws + 64 + 1572864);
        char* P2  = ws + 64 + 1572864 + 786432;
        u16* Qp  = (u16*)P2;
        u16* Kp  = (u16*)(P2 + 393216);
        u16* Vp  = (u16*)(P2 + 786432);
        u16* AOp = (u16*)(P2 + 1179648);
        u16* Hc  = (u16*)P2;

        wire_copy<<<(NX + 255) / 256, blkd, 0, stream>>>(x, d_out, NX, blk);

        for (int b = 0; b < B; b++) {
            size_t ro = (size_t)b * RL;

            ln_kernel<<<L, blkd, 0, stream>>>(d_out, ro, 2, g1, b1, XN, blk);
            for (int p = 0; p < 4; p++) {
                int h = 2 * p;
                gemm_kernel<<<dim3(3, 16), blkd, 0, stream>>>(XN, Wq1, (size_t)h * 96, C, nullptr, 0, Qp, 0, L, 192, C, 0, 1, blk);
                gemm_kernel<<<dim3(3, 16), blkd, 0, stream>>>(XN, Wkv1, (size_t)h * 96, 2 * C, nullptr, 0, Kp, 0, L, 192, C, 0, 1, blk);
                gemm_kernel<<<dim3(3, 16), blkd, 0, stream>>>(XN, Wkv1, (size_t)(C + h * 96), 2 * C, nullptr, 0, Vp, 0, L, 192, C, 0, 1, blk);
                attn_kernel<<<dim3(64, 2), blkd, 0, stream>>>(Qp, Kp, Vp, AOp, 192, 192, 192, 192, 0, 0, 0, blk, b, L, 1);
                gemm_kernel<<<dim3(12, 16), blkd, 0, stream>>>(AOp, Wo1, (size_t)h * 96 * C, C, bo1, 0, d_out, ro, L, C, 192, (p == 0) ? 1 : 0, 3, blk);
            }
            ln_kernel<<<L, blkd, 0, stream>>>(d_out, ro, 2, g2, b2, XN, blk);
            ln_kernel<<<S, blkd, 0, stream>>>(c, (size_t)b * RS, 2, gc, bc, CNb, blk);
            for (int p = 0; p < 4; p++) {
                int h = 2 * p;
                gemm_kernel<<<dim3(3, 16), blkd, 0, stream>>>(XN, Wq2, (size_t)h * 96, C, nullptr, 0, Qp, 0, L, 192, C, 0, 1, blk);
                gemm_kernel<<<dim3(3, 8), blkd, 0, stream>>>(CNb, Wkv2, (size_t)h * 96, 2 * C, nullptr, 0, Kp, 0, S, 192, C, 0, 1, blk);
                gemm_kernel<<<dim3(3, 8), blkd, 0, stream>>>(CNb, Wkv2, (size_t)(C + h * 96), 2 * C, nullptr, 0, Vp, 0, S, 192, C, 0, 1, blk);
                attn_kernel<<<dim3(64, 2), blkd, 0, stream>>>(Qp, Kp, Vp, AOp, 192, 192, 192, 192, 0, 0, 0, blk, b, S, 0);
                gemm_kernel<<<dim3(12, 16), blkd, 0, stream>>>(AOp, Wo2, (size_t)h * 96 * C, C, bo2, 0, d_out, ro, L, C, 192, (p == 0) ? 1 : 0, 3, blk);
            }
            ln_kernel<<<L, blkd, 0, stream>>>(d_out, ro, 2, g4, b4, XN, blk);
            for (int ch = 0; ch < 4; ch++) {
                gemm_kernel<<<dim3(12, 16), blkd, 0, stream>>>(XN, Wf1, (size_t)ch * C, 4 * C, bf1, ch * C, Hc, 0, L, C, C, 1 | 2, 1, blk);
                gemm_kernel<<<dim3(12, 16), blkd, 0, stream>>>(Hc, Wf2, (size_t)ch * C * C, C, bf2, 0, d_out, ro, L, C, C, (ch == 0) ? 1 : 0, 3, blk);
            }
        }
    }
}